// Round 2
// baseline (1166.004 us; speedup 1.0000x reference)
//
#include <hip/hip_runtime.h>

#define NPIX 262144
#define NCLS 19
#define DF 256
#define REPL 16

// workspace layout (float indices)
#define OFF_SUM  0                       // REPL * 4864, permuted layout sigma(d)*19+c
#define OFF_DEN  77824                   // REPL * 19
#define OFF_WSUM 78128                   // REPL
#define OFF_TOT  78144                   // REPL
#define OFF_SEEN 78160                   // 1 (int bitmask)
#define OFF_CENT 78176                   // 4864, row-major c*256+d (cent_safe)
#define MEMSET_BYTES (OFF_CENT * 4)

// -------------------- phase 1: per-class weighted sums --------------------
__global__ __launch_bounds__(256) void k_phase1(
    const float* __restrict__ sfeat, const float* __restrict__ tfeat,
    const float* __restrict__ conf, const int* __restrict__ sarg,
    const int* __restrict__ targ, const int* __restrict__ smask,
    float* __restrict__ ws)
{
    __shared__ float lsum[NCLS * DF];
    __shared__ float lden[NCLS];
    __shared__ float lws;
    const int t = threadIdx.x;
    for (int j = t; j < NCLS * DF; j += 256) lsum[j] = 0.f;
    if (t < NCLS) lden[t] = 0.f;
    if (t == 0) lws = 0.f;
    __syncthreads();

    const int lane = t & 63;
    const int wv = t >> 6;
    const int gBase = blockIdx.x * 1024;   // 512 blocks * 1024 interleaved rows = 2N
    float wloc = 0.f;                      // source mask count (lane 0 only)

    for (int r = wv; r < 1024; r += 4) {
        const int g = gBase + r;           // interleave domains for load balance
        const int i = g >> 1;
        const int dom = g & 1;             // wave-uniform
        int c; float wt;
        if (dom) { c = targ[i]; wt = 1.f - conf[i]; }
        else     { c = sarg[i]; wt = smask[i] ? 1.f : 0.f;   // mask is int32 (bool upload)
                   wloc += (lane == 0) ? wt : 0.f; }
        if (wt != 0.f) {                   // skip unmasked source rows: no feat read
            const float* fr = (dom ? tfeat : sfeat) + i * DF;
            const float4 f = ((const float4*)fr)[lane];
            // dims d = 4*lane+k  ->  lds addr (k*64+lane)*19+c : lane-stride 19, conflict-free
            unsafeAtomicAdd(&lsum[(0 * 64 + lane) * NCLS + c], wt * f.x);
            unsafeAtomicAdd(&lsum[(1 * 64 + lane) * NCLS + c], wt * f.y);
            unsafeAtomicAdd(&lsum[(2 * 64 + lane) * NCLS + c], wt * f.z);
            unsafeAtomicAdd(&lsum[(3 * 64 + lane) * NCLS + c], wt * f.w);
            if (lane == 0) unsafeAtomicAdd(&lden[c], wt);
        }
    }
    if (lane == 0) unsafeAtomicAdd(&lws, wloc);
    __syncthreads();

    const int rep = blockIdx.x & (REPL - 1);
    float* gsum = ws + OFF_SUM + rep * (NCLS * DF);
    for (int j = t; j < NCLS * DF; j += 256) {
        const float v = lsum[j];
        if (v != 0.f) unsafeAtomicAdd(&gsum[j], v);
    }
    if (t < NCLS) unsafeAtomicAdd(&ws[OFF_DEN + rep * NCLS + t], lden[t]);
    if (t == 0)  unsafeAtomicAdd(&ws[OFF_WSUM + rep], lws);
}

// -------------------- finalize centroids --------------------
__global__ __launch_bounds__(256) void k_centroids(float* __restrict__ ws,
                                                   float* __restrict__ out)
{
    const int c = blockIdx.x;      // 19 blocks
    const int d = threadIdx.x;     // 256 dims
    float den = 0.f;
    for (int r = 0; r < REPL; ++r) den += ws[OFF_DEN + r * NCLS + c];
    const bool seen = den > 0.f;
    const int sig = (d & 3) * 64 + (d >> 2);   // same permutation as phase 1
    float s = 0.f;
    for (int r = 0; r < REPL; ++r) s += ws[OFF_SUM + r * (NCLS * DF) + sig * NCLS + c];
    const float centv = seen ? s / fmaxf(den, 1e-12f) : __builtin_inff();
    out[c * DF + d] = centv;                       // reference: inf for unseen
    ws[OFF_CENT + c * DF + d] = seen ? centv : 0.f; // cent_safe for phase 2
    if (d == 0 && seen) atomicOr((int*)ws + OFF_SEEN, 1 << c);
}

// -------------------- phase 2: similarity entropy --------------------
__global__ __launch_bounds__(256) void k_entropy(
    const float* __restrict__ sfeat, const float* __restrict__ tfeat,
    const float* __restrict__ conf, const int* __restrict__ smask,
    float* __restrict__ ws)
{
    __shared__ float cent[NCLS * DF];
    __shared__ int seenSh;
    __shared__ float wacc[4];
    const int t = threadIdx.x;
    for (int j = t; j < NCLS * DF; j += 256) cent[j] = ws[OFF_CENT + j];
    if (t == 0) seenSh = ((const int*)ws)[OFF_SEEN];
    __syncthreads();
    const int seenM = seenSh;

    const int lane = t & 63, wv = t >> 6;
    const int sub = lane & 15, grp = lane >> 4;   // 16 lanes per pixel, 4 px/wave
    const int gBase = blockIdx.x * 256 + wv * 64; // 2048 blocks * 256 px = 2N
    float acc = 0.f;

    for (int it = 0; it < 16; ++it) {
        const int g = gBase + it * 4 + grp;
        const int i = g >> 1;
        const int dom = g & 1;
        float wt;
        if (dom) wt = 1.f - conf[i];
        else     wt = smask[i] ? 1.f : 0.f;       // mask is int32 (bool upload)

        float z[NCLS];
        #pragma unroll
        for (int c = 0; c < NCLS; ++c) z[c] = 0.f;

        if (wt != 0.f) {   // masked source pixels: skip all loads/FMAs
            const float4* fr = (const float4*)((dom ? tfeat : sfeat) + i * DF);
            #pragma unroll
            for (int q = 0; q < 4; ++q) {
                const float4 f = fr[sub + 16 * q];
                const int cb = 4 * sub + 64 * q;
                #pragma unroll
                for (int c = 0; c < NCLS; ++c) {
                    const float4 cc = *(const float4*)&cent[c * DF + cb];
                    z[c] += f.x * cc.x + f.y * cc.y + f.z * cc.z + f.w * cc.w;
                }
            }
        }
        // reduce partial dots across the 16 lanes of this pixel
        #pragma unroll
        for (int c = 0; c < NCLS; ++c) {
            float v = z[c];
            v += __shfl_xor(v, 1);
            v += __shfl_xor(v, 2);
            v += __shfl_xor(v, 4);
            v += __shfl_xor(v, 8);
            z[c] = v;
        }
        // masked log-softmax entropy: ent = sum_seen p*logp
        float m = -3.4e38f;
        #pragma unroll
        for (int c = 0; c < NCLS; ++c)
            if ((seenM >> c) & 1) m = fmaxf(m, z[c]);
        float ssum = 0.f, t1 = 0.f;
        #pragma unroll
        for (int c = 0; c < NCLS; ++c)
            if ((seenM >> c) & 1) {
                const float e = __expf(z[c] - m);
                ssum += e; t1 += e * (z[c] - m);
            }
        const float ent = t1 / ssum - __logf(ssum);
        if (sub == 0 && wt != 0.f) acc += wt * ent;
    }

    // block reduction of weighted entropy sum
    acc += __shfl_xor(acc, 32); acc += __shfl_xor(acc, 16);
    acc += __shfl_xor(acc, 8);  acc += __shfl_xor(acc, 4);
    acc += __shfl_xor(acc, 2);  acc += __shfl_xor(acc, 1);
    if (lane == 0) wacc[wv] = acc;
    __syncthreads();
    if (t == 0)
        unsafeAtomicAdd(&ws[OFF_TOT + (blockIdx.x & (REPL - 1))],
                        wacc[0] + wacc[1] + wacc[2] + wacc[3]);
}

// -------------------- finalize loss --------------------
__global__ void k_loss(const float* __restrict__ ws, float* __restrict__ out)
{
    if (threadIdx.x == 0 && blockIdx.x == 0) {
        float tot = 0.f, wsum = 0.f;
        for (int r = 0; r < REPL; ++r) { tot += ws[OFF_TOT + r]; wsum += ws[OFF_WSUM + r]; }
        out[NCLS * DF] = -tot / (wsum + (float)NPIX);
    }
}

extern "C" void kernel_launch(void* const* d_in, const int* in_sizes, int n_in,
                              void* d_out, int out_size, void* d_ws, size_t ws_size,
                              hipStream_t stream)
{
    const float* sfeat = (const float*)d_in[0];
    const float* tfeat = (const float*)d_in[1];
    const float* conf  = (const float*)d_in[2];
    const int*   sarg  = (const int*)d_in[3];
    const int*   targ  = (const int*)d_in[4];
    const int*   smask = (const int*)d_in[5];
    float* out = (float*)d_out;
    float* ws  = (float*)d_ws;

    hipMemsetAsync(d_ws, 0, MEMSET_BYTES, stream);
    k_phase1   <<<512,  256, 0, stream>>>(sfeat, tfeat, conf, sarg, targ, smask, ws);
    k_centroids<<<NCLS, 256, 0, stream>>>(ws, out);
    k_entropy  <<<2048, 256, 0, stream>>>(sfeat, tfeat, conf, smask, ws);
    k_loss     <<<1,    64,  0, stream>>>(ws, out);
}